// Round 11
// baseline (211.281 us; speedup 1.0000x reference)
//
#include <hip/hip_runtime.h>
#include <hip/hip_bf16.h>

#define N_ROWS 16384
#define D 128
#define QBLK 128
#define KVTILE 32
#define NSPLIT 8
#define KV_PER_SPLIT (N_ROWS / NSPLIT)     // 2048
#define NT (KV_PER_SPLIT / KVTILE)         // 64
#define NTILES (N_ROWS / KVTILE)           // 512
#define LOG2E 1.4426950408889634f
#define SCALE 1.0f
#define LN_EPS 1e-5f
#define L2_EPS 1e-12f

typedef float f32x16 __attribute__((ext_vector_type(16)));
typedef short s16x8 __attribute__((ext_vector_type(8)));
typedef unsigned short u16;

__device__ __forceinline__ u16 f2bf(float f) {
    union { float f; unsigned u; } v; v.f = f;
    unsigned r = v.u + 0x7FFFu + ((v.u >> 16) & 1u);   // RNE
    return (u16)(r >> 16);
}
__device__ __forceinline__ unsigned pk2(float lo, float hi) {
    union { __hip_bfloat162 b; unsigned u; } c;
    c.b = __float22bfloat162_rn(float2{lo, hi});
    return c.u;
}
__device__ __forceinline__ float exp2_hw(float f) {
    return __builtin_amdgcn_exp2f(f);      // v_exp_f32 (base-2)
}

// ---------------- prep: invnrm[i] = 1 / max(||x_i||, eps) ----------------
__global__ __launch_bounds__(256) void prep_norms(const float* __restrict__ x,
                                                  float* __restrict__ invnrm) {
    int t = threadIdx.x;
    int row = blockIdx.x * 64 + (t >> 2);
    int q = t & 3;
    const float4* xr = (const float4*)(x + (size_t)row * D);
    float s = 0.f;
#pragma unroll
    for (int i = 0; i < 8; ++i) {
        float4 v = xr[q * 8 + i];
        s += v.x * v.x + v.y * v.y + v.z * v.z + v.w * v.w;
    }
    s += __shfl_xor(s, 1);
    s += __shfl_xor(s, 2);
    if (q == 0) invnrm[row] = 1.0f / fmaxf(sqrtf(s), L2_EPS);
}

// Kimg: row-major bf16 of normalized x (16384 x 128). Chunk ch (16B) = 8 elems.
__global__ __launch_bounds__(256) void prep_imgK(const float* __restrict__ x,
                                                 const float* __restrict__ invnrm,
                                                 u16* __restrict__ Kimg) {
    int c = blockIdx.x * 256 + threadIdx.x;       // chunk id, 0..262143
    int kv = c >> 4;
    int lc = c & 15;
    const float* p = x + (size_t)kv * D + 8 * lc;
    float inv = invnrm[kv];
    float4 a = *(const float4*)p;
    float4 b = *(const float4*)(p + 4);
    union { unsigned u[4]; s16x8 v; } pk;
    pk.u[0] = pk2(a.x * inv, a.y * inv);
    pk.u[1] = pk2(a.z * inv, a.w * inv);
    pk.u[2] = pk2(b.x * inv, b.y * inv);
    pk.u[3] = pk2(b.z * inv, b.w * inv);
    *(s16x8*)(Kimg + (size_t)c * 8) = pk.v;
}

// VTimg per 32-kv tile (8 KB): chunk (r 0..31, cc 0..15) holds V^T (logical):
//   d = 4r + (cc>>2); kv8 = cc&3; elements e=0..7 -> bf16(x[32*tile + 8*kv8 + e][d]).
__global__ __launch_bounds__(256) void prep_imgVT(const float* __restrict__ x,
                                                  u16* __restrict__ VTimg) {
    __shared__ float sx[KVTILE][D + 4];           // stride 132 floats
    int tile = blockIdx.x;
    int tid = threadIdx.x;
#pragma unroll
    for (int j = 0; j < 4; ++j) {
        int idx = j * 1024 + tid * 4;
        int r = idx >> 7, cc = idx & 127;
        *(float4*)&sx[r][cc] = *(const float4*)(x + (size_t)(tile * KVTILE + r) * D + cc);
    }
    __syncthreads();
#pragma unroll
    for (int j = 0; j < 2; ++j) {
        int ch = j * 256 + tid;                   // 0..511
        int r = ch >> 4, cc = ch & 15;
        int d = 4 * r + (cc >> 2);
        int kv0 = 8 * (cc & 3);
        union { u16 s[8]; s16x8 v; } pk;
#pragma unroll
        for (int e = 0; e < 8; ++e) pk.s[e] = f2bf(sx[kv0 + e][d]);
        *(s16x8*)(VTimg + (size_t)tile * 4096 + (size_t)ch * 8) = pk.v;
    }
}

// 4 waves x 32 q-rows; 3 waves/SIMD target (<=170 regs), 3 blocks/CU by LDS 32KB
__global__ __launch_bounds__(256, 3) void attn(const float* __restrict__ x,
                                               const u16* __restrict__ Kimg,
                                               const u16* __restrict__ VTimg,
                                               const float* __restrict__ invnrm,
                                               float* __restrict__ num,
                                               float* __restrict__ denom) {
    __shared__ __align__(16) u16 sK[2][KVTILE * D];   // 2 x 8 KB
    __shared__ __align__(16) u16 sV[2][KVTILE * D];   // 2 x 8 KB

    const int bx = blockIdx.x;
    const int qb = bx >> 3;
    const int sp = bx & 7;                  // XCD under %8 round-robin
    const int qrow0 = qb * QBLK;
    const int tile0 = sp * NT;

    const int tid = threadIdx.x;
    const int w = tid >> 6;                 // 4 waves, 32 q-rows each
    const int lane = tid & 63;
    const int h = lane >> 5;
    const int ln5 = lane & 31;

    // --- Q B-fragments in registers, scaled by invnrm * log2e ---
    const int q = qrow0 + 32 * w + ln5;
    const float sc = invnrm[q] * LOG2E;
    s16x8 qf[8];
#pragma unroll
    for (int ks = 0; ks < 8; ++ks) {
        const float* p = x + (size_t)q * D + 16 * ks + 8 * h;
        float4 a = *(const float4*)p;
        float4 b = *(const float4*)(p + 4);
        union { unsigned u[4]; s16x8 v; } pk;
        pk.u[0] = pk2(a.x * sc, a.y * sc);
        pk.u[1] = pk2(a.z * sc, a.w * sc);
        pk.u[2] = pk2(b.x * sc, b.y * sc);
        pk.u[3] = pk2(b.z * sc, b.w * sc);
        qf[ks] = pk.v;
    }

    f32x16 acc[4];
#pragma unroll
    for (int dt = 0; dt < 4; ++dt)
#pragma unroll
        for (int r = 0; r < 16; ++r) acc[dt][r] = 0.f;
    float rowsum = 0.f;

    // ---- staging: global (bf16 images) -> regs -> swizzled LDS ----
    s16x8 kst[2], vst[2];
    auto stage_load = [&](int t) {
        const s16x8* kt = (const s16x8*)(Kimg + (size_t)(tile0 + t) * 4096);
        const s16x8* vt = (const s16x8*)(VTimg + (size_t)(tile0 + t) * 4096);
#pragma unroll
        for (int j = 0; j < 2; ++j) {
            kst[j] = kt[j * 256 + tid];
            vst[j] = vt[j * 256 + tid];
        }
    };
    auto stage_write = [&](int buf) {
#pragma unroll
        for (int j = 0; j < 2; ++j) {
            int ch = j * 256 + tid;
            int row = ch >> 4, c16 = ch & 15;
            *(s16x8*)((char*)sK[buf] + row * 256 + 16 * (c16 ^ (row & 15))) = kst[j];
            *(s16x8*)((char*)sV[buf] + row * 256 + 16 * ((c16 + row) & 15)) = vst[j];
        }
    };

    stage_load(0);
    stage_write(0);
    __syncthreads();

    for (int tile = 0; tile < NT; ++tile) {
        const int cur = tile & 1;
        const bool pf = (tile + 1 < NT);
        if (pf) stage_load(tile + 1);       // issue early; lands under compute

        const u16* bK = sK[cur];
        const u16* bV = sV[cur];

        // ---- S^T = K Qn^T over d=128 (32 kv rows), single chain ----
        const char* krow = (const char*)bK + ln5 * 256;
        f32x16 s;
#pragma unroll
        for (int r = 0; r < 16; ++r) s[r] = 0.f;
        __builtin_amdgcn_s_setprio(1);
#pragma unroll
        for (int ks = 0; ks < 8; ++ks) {
            s16x8 kf = *(const s16x8*)(krow + 16 * ((2 * ks + h) ^ (ln5 & 15)));
            s = __builtin_amdgcn_mfma_f32_32x32x16_bf16(kf, qf[ks], s, 0, 0, 0);
        }
        __builtin_amdgcn_s_setprio(0);

        // ---- two 16-kv P-groups: exp2 -> pack -> shfl -> PV ----
#pragma unroll
        for (int pg = 0; pg < 2; ++pg) {
            unsigned d0[2], d1[2], s0[2], s1[2];
#pragma unroll
            for (int mm = 0; mm < 2; ++mm) {
                const int m = 2 * pg + mm;
                float p0 = exp2_hw(s[4 * m + 0]);
                float p1 = exp2_hw(s[4 * m + 1]);
                float p2 = exp2_hw(s[4 * m + 2]);
                float p3 = exp2_hw(s[4 * m + 3]);
                rowsum += (p0 + p1) + (p2 + p3);
                d0[mm] = pk2(p0, p1);
                d1[mm] = pk2(p2, p3);
            }
#pragma unroll
            for (int mm = 0; mm < 2; ++mm) {
                s0[mm] = (unsigned)__shfl_xor((int)d0[mm], 32);
                s1[mm] = (unsigned)__shfl_xor((int)d1[mm], 32);
            }
            union { unsigned u[4]; s16x8 v; } Au;
            Au.u[0] = h ? s0[1] : d0[0];
            Au.u[1] = h ? s1[1] : d1[0];
            Au.u[2] = h ? d0[1] : s0[0];
            Au.u[3] = h ? d1[1] : s1[0];
            __builtin_amdgcn_s_setprio(1);
#pragma unroll
            for (int dt = 0; dt < 4; ++dt) {
                const int rot = 8 * (dt & 1) + (ln5 >> 2);          // r & 15
                const int ccv = (4 * (ln5 & 3) + 2 * pg + h + rot) & 15;
                s16x8 vf = *(const s16x8*)((const char*)bV +
                                           (8 * dt + (ln5 >> 2)) * 256 + 16 * ccv);
                acc[dt] = __builtin_amdgcn_mfma_f32_32x32x16_bf16(Au.v, vf, acc[dt], 0, 0, 0);
            }
            __builtin_amdgcn_s_setprio(0);
        }

        if (pf) stage_write(cur ^ 1);       // write late (T14), then one barrier
        __syncthreads();
    }

    // ---- epilogue: combine partials via device-scope atomics ----
    float tot = rowsum + __shfl_xor(rowsum, 32);
    if (h == 0) atomicAdd(&denom[q], tot);
#pragma unroll
    for (int dt = 0; dt < 4; ++dt)
#pragma unroll
        for (int r = 0; r < 16; ++r) {
            int qr = qrow0 + 32 * w + (r & 3) + 8 * (r >> 2) + 4 * h;
            atomicAdd(&num[(size_t)qr * D + 32 * dt + ln5], acc[dt][r]);
        }
}

// ---------------- finalize: y = 2x - num/denom ; LayerNorm ----------------
__global__ __launch_bounds__(256) void finalize(const float* __restrict__ x,
                                                const float* __restrict__ gamma,
                                                const float* __restrict__ beta,
                                                const float* __restrict__ denom,
                                                float* __restrict__ out) {  // out == num, in place
    int t = threadIdx.x;
    int row = blockIdx.x * 64 + (t >> 2);
    int q = t & 3;
    float invd = 1.0f / denom[row];
    const float4* xr = (const float4*)(x + (size_t)row * D);
    const float4* nr = (const float4*)(out + (size_t)row * D);
    float y[32];
    float s1 = 0.f, s2 = 0.f;
#pragma unroll
    for (int i = 0; i < 8; ++i) {
        float4 xv = xr[q * 8 + i];
        float4 nv = nr[q * 8 + i];
#pragma unroll
        for (int j = 0; j < 4; ++j) {
            float yv = (1.0f + SCALE) * (&xv.x)[j] - SCALE * ((&nv.x)[j] * invd);
            y[i * 4 + j] = yv;
            s1 += yv;
            s2 += yv * yv;
        }
    }
    s1 += __shfl_xor(s1, 1); s1 += __shfl_xor(s1, 2);
    s2 += __shfl_xor(s2, 1); s2 += __shfl_xor(s2, 2);
    float mu = s1 * (1.0f / D);
    float var = s2 * (1.0f / D) - mu * mu;
    float rstd = rsqrtf(var + LN_EPS);
    float4* orow = (float4*)(out + (size_t)row * D);
#pragma unroll
    for (int i = 0; i < 8; ++i) {
        int c = q * 32 + i * 4;
        float4 o;
#pragma unroll
        for (int j = 0; j < 4; ++j)
            (&o.x)[j] = (y[i * 4 + j] - mu) * rstd * gamma[c + j] + beta[c + j];
        orow[q * 8 + i] = o;
    }
}

extern "C" void kernel_launch(void* const* d_in, const int* in_sizes, int n_in,
                              void* d_out, int out_size, void* d_ws, size_t ws_size,
                              hipStream_t stream) {
    const float* x = (const float*)d_in[0];
    const float* gamma = (const float*)d_in[1];
    const float* beta = (const float*)d_in[2];
    float* out = (float*)d_out;

    float* invnrm = (float*)d_ws;                       // 64 KB
    float* denom = invnrm + N_ROWS;                     // 64 KB
    u16* Kimg = (u16*)(denom + N_ROWS);                 // 4 MB
    u16* VTimg = Kimg + (size_t)N_ROWS * D;             // 4 MB  (total ~8.4 MB)

    (void)hipMemsetAsync(d_out, 0, (size_t)N_ROWS * D * sizeof(float), stream);  // num accumulator
    (void)hipMemsetAsync(denom, 0, (size_t)N_ROWS * sizeof(float), stream);

    prep_norms<<<N_ROWS / 64, 256, 0, stream>>>(x, invnrm);
    prep_imgK<<<N_ROWS * 16 / 256, 256, 0, stream>>>(x, invnrm, Kimg);
    prep_imgVT<<<NTILES, 256, 0, stream>>>(x, VTimg);
    attn<<<(N_ROWS / QBLK) * NSPLIT, 256, 0, stream>>>(x, Kimg, VTimg, invnrm, out, denom);
    finalize<<<N_ROWS / 64, 256, 0, stream>>>(x, gamma, beta, denom, out);
}

// Round 12
// 197.792 us; speedup vs baseline: 1.0682x; 1.0682x over previous
//
#include <hip/hip_runtime.h>
#include <hip/hip_bf16.h>

#define N_ROWS 16384
#define D 128
#define QBLK 128
#define KVTILE 32
#define NSPLIT 8
#define KV_PER_SPLIT (N_ROWS / NSPLIT)     // 2048
#define NT (KV_PER_SPLIT / KVTILE)         // 64
#define NTILES (N_ROWS / KVTILE)           // 512
#define LOG2E 1.4426950408889634f
#define SCALE 1.0f
#define LN_EPS 1e-5f
#define L2_EPS 1e-12f

typedef float f32x16 __attribute__((ext_vector_type(16)));
typedef short s16x8 __attribute__((ext_vector_type(8)));
typedef unsigned short u16;

__device__ __forceinline__ u16 f2bf(float f) {
    union { float f; unsigned u; } v; v.f = f;
    unsigned r = v.u + 0x7FFFu + ((v.u >> 16) & 1u);   // RNE
    return (u16)(r >> 16);
}
__device__ __forceinline__ unsigned pk2(float lo, float hi) {
    union { __hip_bfloat162 b; unsigned u; } c;
    c.b = __float22bfloat162_rn(float2{lo, hi});
    return c.u;
}
__device__ __forceinline__ float exp2_hw(float f) {
    return __builtin_amdgcn_exp2f(f);      // v_exp_f32 (base-2)
}

// ---------------- prep: invnrm[i] = 1 / max(||x_i||, eps) ----------------
__global__ __launch_bounds__(256) void prep_norms(const float* __restrict__ x,
                                                  float* __restrict__ invnrm) {
    int t = threadIdx.x;
    int row = blockIdx.x * 64 + (t >> 2);
    int q = t & 3;
    const float4* xr = (const float4*)(x + (size_t)row * D);
    float s = 0.f;
#pragma unroll
    for (int i = 0; i < 8; ++i) {
        float4 v = xr[q * 8 + i];
        s += v.x * v.x + v.y * v.y + v.z * v.z + v.w * v.w;
    }
    s += __shfl_xor(s, 1);
    s += __shfl_xor(s, 2);
    if (q == 0) invnrm[row] = 1.0f / fmaxf(sqrtf(s), L2_EPS);
}

// Kimg: row-major bf16 of normalized x (16384 x 128). Chunk ch (16B) = 8 elems.
__global__ __launch_bounds__(256) void prep_imgK(const float* __restrict__ x,
                                                 const float* __restrict__ invnrm,
                                                 u16* __restrict__ Kimg) {
    int c = blockIdx.x * 256 + threadIdx.x;       // chunk id, 0..262143
    int kv = c >> 4;
    int lc = c & 15;
    const float* p = x + (size_t)kv * D + 8 * lc;
    float inv = invnrm[kv];
    float4 a = *(const float4*)p;
    float4 b = *(const float4*)(p + 4);
    union { unsigned u[4]; s16x8 v; } pk;
    pk.u[0] = pk2(a.x * inv, a.y * inv);
    pk.u[1] = pk2(a.z * inv, a.w * inv);
    pk.u[2] = pk2(b.x * inv, b.y * inv);
    pk.u[3] = pk2(b.z * inv, b.w * inv);
    *(s16x8*)(Kimg + (size_t)c * 8) = pk.v;
}

// VTimg per 32-kv tile (8 KB, 512 chunks of 16B), ordered for per-wave
// coalesced fragment reads: chunk ci = ((pg*4+dt)*2+h)*32 + ln5 holds
// V^T elements j=0..7: bf16(x[32*tile + 16*pg + 8*h + j][32*dt + ln5]).
__global__ __launch_bounds__(256) void prep_imgVT(const float* __restrict__ x,
                                                  u16* __restrict__ VTimg) {
    __shared__ float sx[KVTILE][D + 4];           // stride 132 floats
    int tile = blockIdx.x;
    int tid = threadIdx.x;
#pragma unroll
    for (int j = 0; j < 4; ++j) {
        int idx = j * 1024 + tid * 4;
        int r = idx >> 7, cc = idx & 127;
        *(float4*)&sx[r][cc] = *(const float4*)(x + (size_t)(tile * KVTILE + r) * D + cc);
    }
    __syncthreads();
#pragma unroll
    for (int j = 0; j < 2; ++j) {
        int ci = j * 256 + tid;                   // 0..511
        int ln5c = ci & 31;
        int h = (ci >> 5) & 1;
        int dt = (ci >> 6) & 3;
        int pg = ci >> 8;
        int d = 32 * dt + ln5c;
        int kv0 = 16 * pg + 8 * h;
        union { u16 s[8]; s16x8 v; } pk;
#pragma unroll
        for (int e = 0; e < 8; ++e) pk.s[e] = f2bf(sx[kv0 + e][d]);
        *(s16x8*)(VTimg + (size_t)tile * 4096 + (size_t)ci * 8) = pk.v;
    }
}

// 4 waves x 32 q-rows; K via LDS (16 KB dbuf), V direct from L1/L2
__global__ __launch_bounds__(256, 3) void attn(const float* __restrict__ x,
                                               const u16* __restrict__ Kimg,
                                               const u16* __restrict__ VTimg,
                                               const float* __restrict__ invnrm,
                                               float* __restrict__ num,
                                               float* __restrict__ denom) {
    __shared__ __align__(16) u16 sK[2][KVTILE * D];   // 2 x 8 KB

    const int bx = blockIdx.x;
    const int qb = bx >> 3;
    const int sp = bx & 7;                  // XCD under %8 round-robin
    const int qrow0 = qb * QBLK;
    const int tile0 = sp * NT;

    const int tid = threadIdx.x;
    const int w = tid >> 6;                 // 4 waves, 32 q-rows each
    const int lane = tid & 63;
    const int h = lane >> 5;
    const int ln5 = lane & 31;

    // --- Q B-fragments in registers, scaled by invnrm * log2e ---
    const int q = qrow0 + 32 * w + ln5;
    const float sc = invnrm[q] * LOG2E;
    s16x8 qf[8];
#pragma unroll
    for (int ks = 0; ks < 8; ++ks) {
        const float* p = x + (size_t)q * D + 16 * ks + 8 * h;
        float4 a = *(const float4*)p;
        float4 b = *(const float4*)(p + 4);
        union { unsigned u[4]; s16x8 v; } pk;
        pk.u[0] = pk2(a.x * sc, a.y * sc);
        pk.u[1] = pk2(a.z * sc, a.w * sc);
        pk.u[2] = pk2(b.x * sc, b.y * sc);
        pk.u[3] = pk2(b.z * sc, b.w * sc);
        qf[ks] = pk.v;
    }

    f32x16 acc[4];
#pragma unroll
    for (int dt = 0; dt < 4; ++dt)
#pragma unroll
        for (int r = 0; r < 16; ++r) acc[dt][r] = 0.f;
    float rowsum = 0.f;

    // ---- K staging: global (bf16 image) -> regs -> XOR-swizzled LDS ----
    s16x8 kst[2];
    auto stage_load = [&](int t) {
        const s16x8* kt = (const s16x8*)(Kimg + (size_t)(tile0 + t) * 4096);
#pragma unroll
        for (int j = 0; j < 2; ++j) kst[j] = kt[j * 256 + tid];
    };
    auto stage_write = [&](int buf) {
#pragma unroll
        for (int j = 0; j < 2; ++j) {
            int ch = j * 256 + tid;
            int row = ch >> 4, c16 = ch & 15;
            *(s16x8*)((char*)sK[buf] + row * 256 + 16 * (c16 ^ (row & 15))) = kst[j];
        }
    };

    stage_load(0);
    stage_write(0);
    __syncthreads();

    for (int tile = 0; tile < NT; ++tile) {
        const int cur = tile & 1;
        const bool pf = (tile + 1 < NT);
        if (pf) stage_load(tile + 1);       // issue early; lands under compute

        const u16* bK = sK[cur];
        const s16x8* vt = (const s16x8*)(VTimg + (size_t)(tile0 + tile) * 4096);

        // ---- S^T = K Qn^T over d=128 (32 kv rows) ----
        const char* krow = (const char*)bK + ln5 * 256;
        f32x16 s;
#pragma unroll
        for (int r = 0; r < 16; ++r) s[r] = 0.f;
        __builtin_amdgcn_s_setprio(1);
#pragma unroll
        for (int ks = 0; ks < 8; ++ks) {
            s16x8 kf = *(const s16x8*)(krow + 16 * ((2 * ks + h) ^ (ln5 & 15)));
            s = __builtin_amdgcn_mfma_f32_32x32x16_bf16(kf, qf[ks], s, 0, 0, 0);
        }
        __builtin_amdgcn_s_setprio(0);

        // ---- two 16-kv P-groups: vf loads -> exp2/pack/shfl -> PV ----
#pragma unroll
        for (int pg = 0; pg < 2; ++pg) {
            // V fragments direct from L1/L2 (coalesced 1KB per (pg,dt) read)
            s16x8 vf[4];
#pragma unroll
            for (int dt = 0; dt < 4; ++dt)
                vf[dt] = vt[((pg * 4 + dt) * 2 + h) * 32 + ln5];

            unsigned d0[2], d1[2], s0[2], s1[2];
#pragma unroll
            for (int mm = 0; mm < 2; ++mm) {
                const int m = 2 * pg + mm;
                float p0 = exp2_hw(s[4 * m + 0]);
                float p1 = exp2_hw(s[4 * m + 1]);
                float p2 = exp2_hw(s[4 * m + 2]);
                float p3 = exp2_hw(s[4 * m + 3]);
                rowsum += (p0 + p1) + (p2 + p3);
                d0[mm] = pk2(p0, p1);
                d1[mm] = pk2(p2, p3);
            }
#pragma unroll
            for (int mm = 0; mm < 2; ++mm) {
                s0[mm] = (unsigned)__shfl_xor((int)d0[mm], 32);
                s1[mm] = (unsigned)__shfl_xor((int)d1[mm], 32);
            }
            union { unsigned u[4]; s16x8 v; } Au;
            Au.u[0] = h ? s0[1] : d0[0];
            Au.u[1] = h ? s1[1] : d1[0];
            Au.u[2] = h ? d0[1] : s0[0];
            Au.u[3] = h ? d1[1] : s1[0];
            __builtin_amdgcn_s_setprio(1);
#pragma unroll
            for (int dt = 0; dt < 4; ++dt)
                acc[dt] = __builtin_amdgcn_mfma_f32_32x32x16_bf16(Au.v, vf[dt], acc[dt], 0, 0, 0);
            __builtin_amdgcn_s_setprio(0);
        }

        if (pf) stage_write(cur ^ 1);       // write late (T14), then one barrier
        __syncthreads();
    }

    // ---- epilogue: combine partials via device-scope atomics ----
    float tot = rowsum + __shfl_xor(rowsum, 32);
    if (h == 0) atomicAdd(&denom[q], tot);
#pragma unroll
    for (int dt = 0; dt < 4; ++dt)
#pragma unroll
        for (int r = 0; r < 16; ++r) {
            int qr = qrow0 + 32 * w + (r & 3) + 8 * (r >> 2) + 4 * h;
            atomicAdd(&num[(size_t)qr * D + 32 * dt + ln5], acc[dt][r]);
        }
}

// ---------------- finalize: y = 2x - num/denom ; LayerNorm ----------------
__global__ __launch_bounds__(256) void finalize(const float* __restrict__ x,
                                                const float* __restrict__ gamma,
                                                const float* __restrict__ beta,
                                                const float* __restrict__ denom,
                                                float* __restrict__ out) {  // out == num, in place
    int t = threadIdx.x;
    int row = blockIdx.x * 64 + (t >> 2);
    int q = t & 3;
    float invd = 1.0f / denom[row];
    const float4* xr = (const float4*)(x + (size_t)row * D);
    const float4* nr = (const float4*)(out + (size_t)row * D);
    float y[32];
    float s1 = 0.f, s2 = 0.f;
#pragma unroll
    for (int i = 0; i < 8; ++i) {
        float4 xv = xr[q * 8 + i];
        float4 nv = nr[q * 8 + i];
#pragma unroll
        for (int j = 0; j < 4; ++j) {
            float yv = (1.0f + SCALE) * (&xv.x)[j] - SCALE * ((&nv.x)[j] * invd);
            y[i * 4 + j] = yv;
            s1 += yv;
            s2 += yv * yv;
        }
    }
    s1 += __shfl_xor(s1, 1); s1 += __shfl_xor(s1, 2);
    s2 += __shfl_xor(s2, 1); s2 += __shfl_xor(s2, 2);
    float mu = s1 * (1.0f / D);
    float var = s2 * (1.0f / D) - mu * mu;
    float rstd = rsqrtf(var + LN_EPS);
    float4* orow = (float4*)(out + (size_t)row * D);
#pragma unroll
    for (int i = 0; i < 8; ++i) {
        int c = q * 32 + i * 4;
        float4 o;
#pragma unroll
        for (int j = 0; j < 4; ++j)
            (&o.x)[j] = (y[i * 4 + j] - mu) * rstd * gamma[c + j] + beta[c + j];
        orow[q * 8 + i] = o;
    }
}

extern "C" void kernel_launch(void* const* d_in, const int* in_sizes, int n_in,
                              void* d_out, int out_size, void* d_ws, size_t ws_size,
                              hipStream_t stream) {
    const float* x = (const float*)d_in[0];
    const float* gamma = (const float*)d_in[1];
    const float* beta = (const float*)d_in[2];
    float* out = (float*)d_out;

    float* invnrm = (float*)d_ws;                       // 64 KB
    float* denom = invnrm + N_ROWS;                     // 64 KB
    u16* Kimg = (u16*)(denom + N_ROWS);                 // 4 MB
    u16* VTimg = Kimg + (size_t)N_ROWS * D;             // 4 MB  (total ~8.4 MB)

    (void)hipMemsetAsync(d_out, 0, (size_t)N_ROWS * D * sizeof(float), stream);  // num accumulator
    (void)hipMemsetAsync(denom, 0, (size_t)N_ROWS * sizeof(float), stream);

    prep_norms<<<N_ROWS / 64, 256, 0, stream>>>(x, invnrm);
    prep_imgK<<<N_ROWS * 16 / 256, 256, 0, stream>>>(x, invnrm, Kimg);
    prep_imgVT<<<NTILES, 256, 0, stream>>>(x, VTimg);
    attn<<<(N_ROWS / QBLK) * NSPLIT, 256, 0, stream>>>(x, Kimg, VTimg, invnrm, out, denom);
    finalize<<<N_ROWS / 64, 256, 0, stream>>>(x, gamma, beta, denom, out);
}

// Round 13
// 195.430 us; speedup vs baseline: 1.0811x; 1.0121x over previous
//
#include <hip/hip_runtime.h>
#include <hip/hip_bf16.h>

#define N_ROWS 16384
#define D 128
#define QBLK 128
#define KVTILE 32
#define NSPLIT 4
#define KV_PER_SPLIT (N_ROWS / NSPLIT)     // 4096
#define NT (KV_PER_SPLIT / KVTILE)         // 128
#define NTILES (N_ROWS / KVTILE)           // 512
#define LOG2E 1.4426950408889634f
#define SCALE 1.0f
#define LN_EPS 1e-5f
#define L2_EPS 1e-12f

typedef float f32x16 __attribute__((ext_vector_type(16)));
typedef short s16x8 __attribute__((ext_vector_type(8)));
typedef unsigned short u16;

__device__ __forceinline__ u16 f2bf(float f) {
    union { float f; unsigned u; } v; v.f = f;
    unsigned r = v.u + 0x7FFFu + ((v.u >> 16) & 1u);   // RNE
    return (u16)(r >> 16);
}
__device__ __forceinline__ unsigned pk2(float lo, float hi) {
    union { __hip_bfloat162 b; unsigned u; } c;
    c.b = __float22bfloat162_rn(float2{lo, hi});
    return c.u;
}
__device__ __forceinline__ float exp2_hw(float f) {
    return __builtin_amdgcn_exp2f(f);      // v_exp_f32 (base-2)
}

// ---------------- prep: invnrm[i] = 1 / max(||x_i||, eps) ----------------
__global__ __launch_bounds__(256) void prep_norms(const float* __restrict__ x,
                                                  float* __restrict__ invnrm) {
    int t = threadIdx.x;
    int row = blockIdx.x * 64 + (t >> 2);
    int q = t & 3;
    const float4* xr = (const float4*)(x + (size_t)row * D);
    float s = 0.f;
#pragma unroll
    for (int i = 0; i < 8; ++i) {
        float4 v = xr[q * 8 + i];
        s += v.x * v.x + v.y * v.y + v.z * v.z + v.w * v.w;
    }
    s += __shfl_xor(s, 1);
    s += __shfl_xor(s, 2);
    if (q == 0) invnrm[row] = 1.0f / fmaxf(sqrtf(s), L2_EPS);
}

// Kimg: row-major bf16 of normalized x (16384 x 128). Chunk ch (16B) = 8 elems.
__global__ __launch_bounds__(256) void prep_imgK(const float* __restrict__ x,
                                                 const float* __restrict__ invnrm,
                                                 u16* __restrict__ Kimg) {
    int c = blockIdx.x * 256 + threadIdx.x;       // chunk id, 0..262143
    int kv = c >> 4;
    int lc = c & 15;
    const float* p = x + (size_t)kv * D + 8 * lc;
    float inv = invnrm[kv];
    float4 a = *(const float4*)p;
    float4 b = *(const float4*)(p + 4);
    union { unsigned u[4]; s16x8 v; } pk;
    pk.u[0] = pk2(a.x * inv, a.y * inv);
    pk.u[1] = pk2(a.z * inv, a.w * inv);
    pk.u[2] = pk2(b.x * inv, b.y * inv);
    pk.u[3] = pk2(b.z * inv, b.w * inv);
    *(s16x8*)(Kimg + (size_t)c * 8) = pk.v;
}

// VTimg per 32-kv tile (8 KB, 512 chunks of 16B), ordered for per-wave
// coalesced fragment reads: chunk ci = ((pg*4+dt)*2+h)*32 + ln5 holds
// V^T elements j=0..7: bf16(x[32*tile + 16*pg + 8*h + j][32*dt + ln5]).
__global__ __launch_bounds__(256) void prep_imgVT(const float* __restrict__ x,
                                                  u16* __restrict__ VTimg) {
    __shared__ float sx[KVTILE][D + 4];           // stride 132 floats
    int tile = blockIdx.x;
    int tid = threadIdx.x;
#pragma unroll
    for (int j = 0; j < 4; ++j) {
        int idx = j * 1024 + tid * 4;
        int r = idx >> 7, cc = idx & 127;
        *(float4*)&sx[r][cc] = *(const float4*)(x + (size_t)(tile * KVTILE + r) * D + cc);
    }
    __syncthreads();
#pragma unroll
    for (int j = 0; j < 2; ++j) {
        int ci = j * 256 + tid;                   // 0..511
        int ln5c = ci & 31;
        int h = (ci >> 5) & 1;
        int dt = (ci >> 6) & 3;
        int pg = ci >> 8;
        int d = 32 * dt + ln5c;
        int kv0 = 16 * pg + 8 * h;
        union { u16 s[8]; s16x8 v; } pk;
#pragma unroll
        for (int e = 0; e < 8; ++e) pk.s[e] = f2bf(sx[kv0 + e][d]);
        *(s16x8*)(VTimg + (size_t)tile * 4096 + (size_t)ci * 8) = pk.v;
    }
}

// 4 waves x 32 q-rows; T15 double pipeline: QK^T(t+1) overlaps softmax/PV(t)
__global__ __launch_bounds__(256, 2) void attn(const float* __restrict__ x,
                                               const u16* __restrict__ Kimg,
                                               const u16* __restrict__ VTimg,
                                               const float* __restrict__ invnrm,
                                               float* __restrict__ num,
                                               float* __restrict__ denom) {
    __shared__ __align__(16) u16 sK[2][KVTILE * D];   // 2 x 8 KB; K(j) in buf[j&1]

    const int bx = blockIdx.x;
    const int qb = bx >> 2;
    const int sp = bx & 3;                  // one split per XCD (bx%8 dispatch)
    const int qrow0 = qb * QBLK;
    const int tile0 = sp * NT;

    const int tid = threadIdx.x;
    const int w = tid >> 6;                 // 4 waves, 32 q-rows each
    const int lane = tid & 63;
    const int h = lane >> 5;
    const int ln5 = lane & 31;

    // --- Q B-fragments in registers, scaled by invnrm * log2e ---
    const int q = qrow0 + 32 * w + ln5;
    const float sc = invnrm[q] * LOG2E;
    s16x8 qf[8];
#pragma unroll
    for (int ks = 0; ks < 8; ++ks) {
        const float* p = x + (size_t)q * D + 16 * ks + 8 * h;
        float4 a = *(const float4*)p;
        float4 b = *(const float4*)(p + 4);
        union { unsigned u[4]; s16x8 v; } pk;
        pk.u[0] = pk2(a.x * sc, a.y * sc);
        pk.u[1] = pk2(a.z * sc, a.w * sc);
        pk.u[2] = pk2(b.x * sc, b.y * sc);
        pk.u[3] = pk2(b.z * sc, b.w * sc);
        qf[ks] = pk.v;
    }

    f32x16 acc[4];
#pragma unroll
    for (int dt = 0; dt < 4; ++dt)
#pragma unroll
        for (int r = 0; r < 16; ++r) acc[dt][r] = 0.f;
    float rowsum = 0.f;

    // ---- K staging: global (bf16 image) -> regs -> XOR-swizzled LDS ----
    s16x8 kst[2];
    auto stage_load = [&](int t) {
        const s16x8* kt = (const s16x8*)(Kimg + (size_t)(tile0 + t) * 4096);
#pragma unroll
        for (int j = 0; j < 2; ++j) kst[j] = kt[j * 256 + tid];
    };
    auto stage_write = [&](int buf) {
#pragma unroll
        for (int j = 0; j < 2; ++j) {
            int ch = j * 256 + tid;
            int row = ch >> 4, c16 = ch & 15;
            *(s16x8*)((char*)sK[buf] + row * 256 + 16 * (c16 ^ (row & 15))) = kst[j];
        }
    };

    // ---- QK^T for one staged tile -> per-lane S^T column (16 f32) ----
    auto qkt = [&](const u16* bK) -> f32x16 {
        const char* krow = (const char*)bK + ln5 * 256;
        f32x16 s;
#pragma unroll
        for (int r = 0; r < 16; ++r) s[r] = 0.f;
        __builtin_amdgcn_s_setprio(1);
#pragma unroll
        for (int ks = 0; ks < 8; ++ks) {
            s16x8 kf = *(const s16x8*)(krow + 16 * ((2 * ks + h) ^ (ln5 & 15)));
            s = __builtin_amdgcn_mfma_f32_32x32x16_bf16(kf, qf[ks], s, 0, 0, 0);
        }
        __builtin_amdgcn_s_setprio(0);
        return s;
    };

    // ---- softmax + PV for one tile (V direct from L1/L2) ----
    auto softmax_pv = [&](const f32x16& s, int tile) {
        const s16x8* vt = (const s16x8*)(VTimg + (size_t)(tile0 + tile) * 4096);
#pragma unroll
        for (int pg = 0; pg < 2; ++pg) {
            s16x8 vf[4];
#pragma unroll
            for (int dt = 0; dt < 4; ++dt)
                vf[dt] = vt[((pg * 4 + dt) * 2 + h) * 32 + ln5];

            unsigned d0[2], d1[2], s0[2], s1[2];
#pragma unroll
            for (int mm = 0; mm < 2; ++mm) {
                const int m = 2 * pg + mm;
                float p0 = exp2_hw(s[4 * m + 0]);
                float p1 = exp2_hw(s[4 * m + 1]);
                float p2 = exp2_hw(s[4 * m + 2]);
                float p3 = exp2_hw(s[4 * m + 3]);
                rowsum += (p0 + p1) + (p2 + p3);
                d0[mm] = pk2(p0, p1);
                d1[mm] = pk2(p2, p3);
            }
#pragma unroll
            for (int mm = 0; mm < 2; ++mm) {
                s0[mm] = (unsigned)__shfl_xor((int)d0[mm], 32);
                s1[mm] = (unsigned)__shfl_xor((int)d1[mm], 32);
            }
            union { unsigned u[4]; s16x8 v; } Au;
            Au.u[0] = h ? s0[1] : d0[0];
            Au.u[1] = h ? s1[1] : d1[0];
            Au.u[2] = h ? d0[1] : s0[0];
            Au.u[3] = h ? d1[1] : s1[0];
            __builtin_amdgcn_s_setprio(1);
#pragma unroll
            for (int dt = 0; dt < 4; ++dt)
                acc[dt] = __builtin_amdgcn_mfma_f32_32x32x16_bf16(Au.v, vf[dt], acc[dt], 0, 0, 0);
            __builtin_amdgcn_s_setprio(0);
        }
    };

    // ---- prologue: stage K(0), K(1); compute QK^T(0) ----
    stage_load(0); stage_write(0);
    stage_load(1); stage_write(1);
    __syncthreads();
    f32x16 sA = qkt(sK[0]);
    f32x16 sB;

    // ---- main loop, 2 tiles per iteration (static sA/sB roles) ----
    for (int t = 0; t < NT; t += 2) {
        // iter A: tile t (sA live), QK^T(t+1) overlaps softmax/PV(t)
        if (t + 2 < NT) stage_load(t + 2);
        sB = qkt(sK[1]);                       // K(t+1) in buf1
        softmax_pv(sA, t);
        if (t + 2 < NT) stage_write(0);        // K(t+2) -> buf0
        __syncthreads();
        // iter B: tile t+1 (sB live), QK^T(t+2) overlaps softmax/PV(t+1)
        if (t + 3 < NT) stage_load(t + 3);
        if (t + 2 < NT) sA = qkt(sK[0]);       // K(t+2) in buf0
        softmax_pv(sB, t + 1);
        if (t + 3 < NT) stage_write(1);        // K(t+3) -> buf1
        __syncthreads();
    }

    // ---- epilogue: combine partials via device-scope atomics ----
    float tot = rowsum + __shfl_xor(rowsum, 32);
    if (h == 0) atomicAdd(&denom[q], tot);
#pragma unroll
    for (int dt = 0; dt < 4; ++dt)
#pragma unroll
        for (int r = 0; r < 16; ++r) {
            int qr = qrow0 + 32 * w + (r & 3) + 8 * (r >> 2) + 4 * h;
            atomicAdd(&num[(size_t)qr * D + 32 * dt + ln5], acc[dt][r]);
        }
}

// ---------------- finalize: y = 2x - num/denom ; LayerNorm ----------------
__global__ __launch_bounds__(256) void finalize(const float* __restrict__ x,
                                                const float* __restrict__ gamma,
                                                const float* __restrict__ beta,
                                                const float* __restrict__ denom,
                                                float* __restrict__ out) {  // out == num, in place
    int t = threadIdx.x;
    int row = blockIdx.x * 64 + (t >> 2);
    int q = t & 3;
    float invd = 1.0f / denom[row];
    const float4* xr = (const float4*)(x + (size_t)row * D);
    const float4* nr = (const float4*)(out + (size_t)row * D);
    float y[32];
    float s1 = 0.f, s2 = 0.f;
#pragma unroll
    for (int i = 0; i < 8; ++i) {
        float4 xv = xr[q * 8 + i];
        float4 nv = nr[q * 8 + i];
#pragma unroll
        for (int j = 0; j < 4; ++j) {
            float yv = (1.0f + SCALE) * (&xv.x)[j] - SCALE * ((&nv.x)[j] * invd);
            y[i * 4 + j] = yv;
            s1 += yv;
            s2 += yv * yv;
        }
    }
    s1 += __shfl_xor(s1, 1); s1 += __shfl_xor(s1, 2);
    s2 += __shfl_xor(s2, 1); s2 += __shfl_xor(s2, 2);
    float mu = s1 * (1.0f / D);
    float var = s2 * (1.0f / D) - mu * mu;
    float rstd = rsqrtf(var + LN_EPS);
    float4* orow = (float4*)(out + (size_t)row * D);
#pragma unroll
    for (int i = 0; i < 8; ++i) {
        int c = q * 32 + i * 4;
        float4 o;
#pragma unroll
        for (int j = 0; j < 4; ++j)
            (&o.x)[j] = (y[i * 4 + j] - mu) * rstd * gamma[c + j] + beta[c + j];
        orow[q * 8 + i] = o;
    }
}

extern "C" void kernel_launch(void* const* d_in, const int* in_sizes, int n_in,
                              void* d_out, int out_size, void* d_ws, size_t ws_size,
                              hipStream_t stream) {
    const float* x = (const float*)d_in[0];
    const float* gamma = (const float*)d_in[1];
    const float* beta = (const float*)d_in[2];
    float* out = (float*)d_out;

    float* invnrm = (float*)d_ws;                       // 64 KB
    float* denom = invnrm + N_ROWS;                     // 64 KB
    u16* Kimg = (u16*)(denom + N_ROWS);                 // 4 MB
    u16* VTimg = Kimg + (size_t)N_ROWS * D;             // 4 MB  (total ~8.4 MB)

    (void)hipMemsetAsync(d_out, 0, (size_t)N_ROWS * D * sizeof(float), stream);  // num accumulator
    (void)hipMemsetAsync(denom, 0, (size_t)N_ROWS * sizeof(float), stream);

    prep_norms<<<N_ROWS / 64, 256, 0, stream>>>(x, invnrm);
    prep_imgK<<<N_ROWS * 16 / 256, 256, 0, stream>>>(x, invnrm, Kimg);
    prep_imgVT<<<NTILES, 256, 0, stream>>>(x, VTimg);
    attn<<<(N_ROWS / QBLK) * NSPLIT, 256, 0, stream>>>(x, Kimg, VTimg, invnrm, out, denom);
    finalize<<<N_ROWS / 64, 256, 0, stream>>>(x, gamma, beta, denom, out);
}